// Round 1
// baseline (1801.762 us; speedup 1.0000x reference)
//
#include <hip/hip_runtime.h>
#include <hip/hip_bf16.h>
#include <cstdint>

typedef __attribute__((ext_vector_type(8))) short short8;
typedef __attribute__((ext_vector_type(4))) float f32x4;

#define K2     2048     // split K (1024 hi + 1024 lo)
#define D_DIM  1024
#define M_TOT  16384    // B*L
#define L_DIM  4096

__constant__ int c_offs[9] = {0, -32, -16, -4, -1, 1, 4, 16, 32};

// ---------- split f32 -> bf16 hi|lo, layout [rows][2048] (hi at k, lo at 1024+k) ----------
__global__ __launch_bounds__(256) void split_kernel(const float* __restrict__ src,
                                                    unsigned short* __restrict__ dst,
                                                    long total /* rows*1024 */)
{
    long i4 = ((long)blockIdx.x * 256 + threadIdx.x) * 4;
    if (i4 >= total) return;
    long m = i4 >> 10;
    int  k = (int)(i4 & 1023);
    float4 f = *(const float4*)&src[i4];
    float fv0 = f.x, fv1 = f.y, fv2 = f.z, fv3 = f.w;
    ushort4 hi, lo;
    {
        __hip_bfloat16 h0 = __float2bfloat16(fv0), h1 = __float2bfloat16(fv1),
                       h2 = __float2bfloat16(fv2), h3 = __float2bfloat16(fv3);
        __hip_bfloat16 l0 = __float2bfloat16(fv0 - __bfloat162float(h0));
        __hip_bfloat16 l1 = __float2bfloat16(fv1 - __bfloat162float(h1));
        __hip_bfloat16 l2 = __float2bfloat16(fv2 - __bfloat162float(h2));
        __hip_bfloat16 l3 = __float2bfloat16(fv3 - __bfloat162float(h3));
        hi.x = *(unsigned short*)&h0; hi.y = *(unsigned short*)&h1;
        hi.z = *(unsigned short*)&h2; hi.w = *(unsigned short*)&h3;
        lo.x = *(unsigned short*)&l0; lo.y = *(unsigned short*)&l1;
        lo.z = *(unsigned short*)&l2; lo.w = *(unsigned short*)&l3;
    }
    *(ushort4*)&dst[m * K2 + k]        = hi;
    *(ushort4*)&dst[m * K2 + 1024 + k] = lo;
}

// ---------- 128x128 GEMM tile core: A [M][2048] bf16, Bm rows = output cols, [*][2048] ----------
__device__ __forceinline__ void gemm_tile(const unsigned short* __restrict__ A,
                                          const unsigned short* __restrict__ Bm,
                                          int m0,
                                          unsigned short* As, unsigned short* Bs,
                                          f32x4 acc[4][4])
{
    const int tid  = threadIdx.x;
    const int lane = tid & 63;
    const int wid  = tid >> 6;
    const int wr = wid >> 1, wc = wid & 1;
    const int trow = tid >> 2;   // 0..63
    const int tq   = tid & 3;    // 16B chunk within 64B row
    const int lg = lane >> 4;    // 0..3 (k-group)
    const int lr = lane & 15;    // row/col within fragment

    const size_t a_base = (size_t)(m0 + trow) * K2 + tq * 8;
    const size_t b_base = (size_t)trow * K2 + tq * 8;

    for (int kt = 0; kt < K2 / 32; ++kt) {
        const int k0 = kt * 32;
        // stage A (128x32) and B (128x32) tiles: 4 x 16B per thread
        *(uint4*)&As[trow * 32 + tq * 8]        = *(const uint4*)&A[a_base + k0];
        *(uint4*)&As[(trow + 64) * 32 + tq * 8] = *(const uint4*)&A[a_base + (size_t)64 * K2 + k0];
        *(uint4*)&Bs[trow * 32 + tq * 8]        = *(const uint4*)&Bm[b_base + k0];
        *(uint4*)&Bs[(trow + 64) * 32 + tq * 8] = *(const uint4*)&Bm[b_base + (size_t)64 * K2 + k0];
        __syncthreads();

        short8 af[4], bf[4];
#pragma unroll
        for (int i = 0; i < 4; ++i)
            af[i] = *(const short8*)&As[(wr * 64 + i * 16 + lr) * 32 + lg * 8];
#pragma unroll
        for (int i = 0; i < 4; ++i)
            bf[i] = *(const short8*)&Bs[(wc * 64 + i * 16 + lr) * 32 + lg * 8];
#pragma unroll
        for (int i = 0; i < 4; ++i)
#pragma unroll
            for (int j = 0; j < 4; ++j)
                acc[i][j] = __builtin_amdgcn_mfma_f32_16x16x32_bf16(af[i], bf[j], acc[i][j], 0, 0, 0);
        __syncthreads();
    }
}

// ---------- v = x @ value_W^T ----------
__global__ __launch_bounds__(256) void v_gemm(const unsigned short* __restrict__ A,
                                              const unsigned short* __restrict__ Bv,
                                              float* __restrict__ v_out)
{
    __shared__ __align__(16) unsigned short As[128 * 32];
    __shared__ __align__(16) unsigned short Bs[128 * 32];
    const int m0 = blockIdx.y * 128;
    const int e0 = blockIdx.x * 128;
    f32x4 acc[4][4];
#pragma unroll
    for (int i = 0; i < 4; ++i)
#pragma unroll
        for (int j = 0; j < 4; ++j)
            acc[i][j] = {0.f, 0.f, 0.f, 0.f};

    gemm_tile(A, Bv + (size_t)e0 * K2, m0, As, Bs, acc);

    const int lane = threadIdx.x & 63, wid = threadIdx.x >> 6;
    const int wr = wid >> 1, wc = wid & 1, lg = lane >> 4, lr = lane & 15;
#pragma unroll
    for (int i = 0; i < 4; ++i)
#pragma unroll
        for (int j = 0; j < 4; ++j)
#pragma unroll
            for (int r = 0; r < 4; ++r) {
                int row = m0 + wr * 64 + i * 16 + lg * 4 + r;
                int col = e0 + wc * 64 + j * 16 + lr;
                v_out[(size_t)row * D_DIM + col] = acc[i][j][r];
            }
}

// ---------- gates GEMM + sigmoid + shift-gather + sum over 9 ----------
__global__ __launch_bounds__(256) void gates_gemm(const unsigned short* __restrict__ A,
                                                  const unsigned short* __restrict__ Bg,
                                                  const float* __restrict__ v_ws,
                                                  float* __restrict__ out)
{
    __shared__ __align__(16) unsigned short As[128 * 32];
    __shared__ __align__(16) unsigned short Bs[128 * 32];
    const int m0 = blockIdx.y * 128;
    const int d0 = blockIdx.x * 128;
    const int lane = threadIdx.x & 63, wid = threadIdx.x >> 6;
    const int wr = wid >> 1, wc = wid & 1, lg = lane >> 4, lr = lane & 15;

    float oacc[4][4][4];
#pragma unroll
    for (int i = 0; i < 4; ++i)
#pragma unroll
        for (int j = 0; j < 4; ++j)
#pragma unroll
            for (int r = 0; r < 4; ++r)
                oacc[i][j][r] = 0.f;

    for (int k = 0; k < 9; ++k) {
        f32x4 acc[4][4];
#pragma unroll
        for (int i = 0; i < 4; ++i)
#pragma unroll
            for (int j = 0; j < 4; ++j)
                acc[i][j] = {0.f, 0.f, 0.f, 0.f};

        gemm_tile(A, Bg + ((size_t)k * D_DIM + d0) * K2, m0, As, Bs, acc);

        const int s = c_offs[k];
#pragma unroll
        for (int i = 0; i < 4; ++i)
#pragma unroll
            for (int j = 0; j < 4; ++j)
#pragma unroll
                for (int r = 0; r < 4; ++r) {
                    int row = m0 + wr * 64 + i * 16 + lg * 4 + r;
                    int col = d0 + wc * 64 + j * 16 + lr;
                    int srow = (row & ~(L_DIM - 1)) | ((row + s + L_DIM) & (L_DIM - 1));
                    float g = 1.f / (1.f + __expf(-acc[i][j][r]));
                    oacc[i][j][r] += g * v_ws[(size_t)srow * D_DIM + col];
                }
    }

#pragma unroll
    for (int i = 0; i < 4; ++i)
#pragma unroll
        for (int j = 0; j < 4; ++j)
#pragma unroll
            for (int r = 0; r < 4; ++r) {
                int row = m0 + wr * 64 + i * 16 + lg * 4 + r;
                int col = d0 + wc * 64 + j * 16 + lr;
                out[(size_t)row * D_DIM + col] = oacc[i][j][r];
            }
}

// ---------- in-place LayerNorm over last dim ----------
__global__ __launch_bounds__(256) void ln_kernel(float* __restrict__ out,
                                                 const float* __restrict__ gamma,
                                                 const float* __restrict__ beta)
{
    const int row = blockIdx.x;
    const int tid = threadIdx.x;
    float4 v = *(float4*)&out[(size_t)row * D_DIM + tid * 4];
    float s  = v.x + v.y + v.z + v.w;
    float s2 = v.x * v.x + v.y * v.y + v.z * v.z + v.w * v.w;
#pragma unroll
    for (int off = 32; off > 0; off >>= 1) {
        s  += __shfl_down(s, off, 64);
        s2 += __shfl_down(s2, off, 64);
    }
    __shared__ float sh[8];
    const int wid = tid >> 6, lane = tid & 63;
    if (lane == 0) { sh[wid] = s; sh[4 + wid] = s2; }
    __syncthreads();
    if (tid == 0) {
        float ts = sh[0] + sh[1] + sh[2] + sh[3];
        float t2 = sh[4] + sh[5] + sh[6] + sh[7];
        sh[0] = ts; sh[1] = t2;
    }
    __syncthreads();
    const float mean = sh[0] * (1.f / (float)D_DIM);
    const float var  = sh[1] * (1.f / (float)D_DIM) - mean * mean;
    const float inv  = rsqrtf(var + 1e-5f);
    float4 g = *(const float4*)&gamma[tid * 4];
    float4 b = *(const float4*)&beta[tid * 4];
    v.x = (v.x - mean) * inv * g.x + b.x;
    v.y = (v.y - mean) * inv * g.y + b.y;
    v.z = (v.z - mean) * inv * g.z + b.z;
    v.w = (v.w - mean) * inv * g.w + b.w;
    *(float4*)&out[(size_t)row * D_DIM + tid * 4] = v;
}

extern "C" void kernel_launch(void* const* d_in, const int* in_sizes, int n_in,
                              void* d_out, int out_size, void* d_ws, size_t ws_size,
                              hipStream_t stream) {
    const float* x       = (const float*)d_in[0];   // (4,4096,1024)
    const float* gate_W  = (const float*)d_in[1];   // (9216,1024)
    const float* value_W = (const float*)d_in[2];   // (1024,1024)
    const float* gamma   = (const float*)d_in[3];   // (1024,)
    const float* beta    = (const float*)d_in[4];   // (1024,)
    float* out = (float*)d_out;                     // (4,4096,1024) f32

    char* ws = (char*)d_ws;
    unsigned short* a_split = (unsigned short*)ws;                       // 64 MB
    unsigned short* bw_v    = (unsigned short*)(ws + 67108864);          //  4 MB
    unsigned short* bw_g    = (unsigned short*)(ws + 71303168);          // 36 MB
    float*          v_ws    = (float*)(ws + 109051904);                  // 64 MB

    // 1. split x / weights into bf16 hi|lo (K doubled to 2048)
    split_kernel<<<16384, 256, 0, stream>>>(x,       a_split, (long)M_TOT * 1024);
    split_kernel<<<1024,  256, 0, stream>>>(value_W, bw_v,    (long)1024  * 1024);
    split_kernel<<<9216,  256, 0, stream>>>(gate_W,  bw_g,    (long)9216  * 1024);

    // 2. v = x @ value_W^T   (M=16384, N=1024, K=2048)
    v_gemm<<<dim3(8, 128), 256, 0, stream>>>(a_split, bw_v, v_ws);

    // 3. gates GEMM + sigmoid + shifted-v gather + sum_k  -> pre-LN out
    gates_gemm<<<dim3(8, 128), 256, 0, stream>>>(a_split, bw_g, v_ws, out);

    // 4. LayerNorm in place
    ln_kernel<<<16384, 256, 0, stream>>>(out, gamma, beta);
}

// Round 3
// 1049.425 us; speedup vs baseline: 1.7169x; 1.7169x over previous
//
#include <hip/hip_runtime.h>
#include <hip/hip_bf16.h>
#include <cstdint>

typedef __attribute__((ext_vector_type(8))) short short8;
typedef __attribute__((ext_vector_type(4))) float f32x4;

#define KD     1024     // GEMM K (plain bf16, no split)
#define D_DIM  1024
#define M_TOT  16384    // B*L
#define L_DIM  4096

__constant__ int c_offs[9] = {0, -32, -16, -4, -1, 1, 4, 16, 32};

// async global->LDS, 16B per lane. LDS dest must be wave-uniform base; HW adds lane*16.
__device__ __forceinline__ void gload_lds16(const unsigned short* g, unsigned short* l) {
    __builtin_amdgcn_global_load_lds((const __attribute__((address_space(1))) unsigned int*)(g),
                                     (__attribute__((address_space(3))) unsigned int*)(l),
                                     16, 0, 0);
}

// ---------- f32 -> bf16 convert ----------
__global__ __launch_bounds__(256) void cvt_kernel(const float* __restrict__ src,
                                                  unsigned short* __restrict__ dst,
                                                  long total)
{
    long i4 = ((long)blockIdx.x * 256 + threadIdx.x) * 4;
    if (i4 >= total) return;
    float4 f = *(const float4*)&src[i4];
    __hip_bfloat16 h0 = __float2bfloat16(f.x), h1 = __float2bfloat16(f.y),
                   h2 = __float2bfloat16(f.z), h3 = __float2bfloat16(f.w);
    ushort4 h;
    h.x = *(unsigned short*)&h0; h.y = *(unsigned short*)&h1;
    h.z = *(unsigned short*)&h2; h.w = *(unsigned short*)&h3;
    *(ushort4*)&dst[i4] = h;
}

// ---------- 128x128 GEMM tile core ----------
// LDS tile layout: [row 0..127][slot 0..3][8 bf16], where slot s of row r holds
// k-chunk (s ^ ((r>>1)&3)) — involution swizzle applied at BOTH the global source
// (staging) and the ds_read, making 16-lane read phases bank-quad-uniform (free).
__device__ __forceinline__ void gemm_tile(const unsigned short* __restrict__ A,
                                          const unsigned short* __restrict__ Bm,
                                          int m0,
                                          unsigned short* As, unsigned short* Bs,
                                          f32x4 acc[4][4])
{
    const int tid  = threadIdx.x;
    const int lane = tid & 63;
    const int wid  = tid >> 6;
    const int wr = wid >> 1, wc = wid & 1;
    const int lg = lane >> 4, lr = lane & 15;

    // staging: instr t covers LDS bytes [t*1024, t*1024+1024) = rows t*16..t*16+15.
    // wave wid issues t = 2*wid and 2*wid+1 for A and for B.
    const int t0   = wid * 2;
    const int row0 = t0 * 16 + (lane >> 2);
    const int row1 = row0 + 16;
    const int sch  = lane & 3;
    const int kc0  = sch ^ ((row0 >> 1) & 3);   // pre-swizzled k-chunk for this lane
    const int kc1  = sch ^ ((row1 >> 1) & 3);

    const unsigned short* gA0 = A  + (size_t)(m0 + row0) * KD + kc0 * 8;
    const unsigned short* gA1 = A  + (size_t)(m0 + row1) * KD + kc1 * 8;
    const unsigned short* gB0 = Bm + (size_t)row0 * KD + kc0 * 8;
    const unsigned short* gB1 = Bm + (size_t)row1 * KD + kc1 * 8;

    unsigned short* lA0 = As + t0 * 512;        // 512 ushort = 1024 B
    unsigned short* lA1 = As + (t0 + 1) * 512;
    unsigned short* lB0 = Bs + t0 * 512;
    unsigned short* lB1 = Bs + (t0 + 1) * 512;

    const int raBase = wr * 64 + lr;
    const int rbBase = wc * 64 + lr;

    for (int kt = 0; kt < KD / 32; ++kt) {
        const int k0 = kt * 32;
        gload_lds16(gA0 + k0, lA0);
        gload_lds16(gA1 + k0, lA1);
        gload_lds16(gB0 + k0, lB0);
        gload_lds16(gB1 + k0, lB1);
        __syncthreads();   // compiler emits vmcnt(0) drain before s_barrier

        short8 af[4], bfr[4];
#pragma unroll
        for (int i = 0; i < 4; ++i) {
            int ra = raBase + i * 16;
            int sa = lg ^ ((ra >> 1) & 3);
            af[i] = *(const short8*)&As[ra * 32 + sa * 8];
        }
#pragma unroll
        for (int j = 0; j < 4; ++j) {
            int rb = rbBase + j * 16;
            int sb = lg ^ ((rb >> 1) & 3);
            bfr[j] = *(const short8*)&Bs[rb * 32 + sb * 8];
        }
#pragma unroll
        for (int i = 0; i < 4; ++i)
#pragma unroll
            for (int j = 0; j < 4; ++j)
                acc[i][j] = __builtin_amdgcn_mfma_f32_16x16x32_bf16(af[i], bfr[j], acc[i][j], 0, 0, 0);
        __syncthreads();
    }
}

// ---------- v = x @ value_W^T ----------
__global__ __launch_bounds__(256) void v_gemm(const unsigned short* __restrict__ A,
                                              const unsigned short* __restrict__ Bv,
                                              float* __restrict__ v_out)
{
    __shared__ __align__(16) unsigned short As[128 * 32];
    __shared__ __align__(16) unsigned short Bs[128 * 32];
    const int m0 = blockIdx.y * 128;
    const int e0 = blockIdx.x * 128;
    f32x4 acc[4][4];
#pragma unroll
    for (int i = 0; i < 4; ++i)
#pragma unroll
        for (int j = 0; j < 4; ++j)
            acc[i][j] = {0.f, 0.f, 0.f, 0.f};

    gemm_tile(A, Bv + (size_t)e0 * KD, m0, As, Bs, acc);

    const int lane = threadIdx.x & 63, wid = threadIdx.x >> 6;
    const int wr = wid >> 1, wc = wid & 1, lg = lane >> 4, lr = lane & 15;
#pragma unroll
    for (int i = 0; i < 4; ++i)
#pragma unroll
        for (int j = 0; j < 4; ++j)
#pragma unroll
            for (int r = 0; r < 4; ++r) {
                int row = m0 + wr * 64 + i * 16 + lg * 4 + r;
                int col = e0 + wc * 64 + j * 16 + lr;
                v_out[(size_t)row * D_DIM + col] = acc[i][j][r];
            }
}

// ---------- gates GEMM + sigmoid + shift-gather + sum over 9 ----------
__global__ __launch_bounds__(256) void gates_gemm(const unsigned short* __restrict__ A,
                                                  const unsigned short* __restrict__ Bg,
                                                  const float* __restrict__ v_ws,
                                                  float* __restrict__ out)
{
    __shared__ __align__(16) unsigned short As[128 * 32];
    __shared__ __align__(16) unsigned short Bs[128 * 32];
    const int m0 = blockIdx.y * 128;
    const int d0 = blockIdx.x * 128;
    const int lane = threadIdx.x & 63, wid = threadIdx.x >> 6;
    const int wr = wid >> 1, wc = wid & 1, lg = lane >> 4, lr = lane & 15;

    float oacc[4][4][4];
#pragma unroll
    for (int i = 0; i < 4; ++i)
#pragma unroll
        for (int j = 0; j < 4; ++j)
#pragma unroll
            for (int r = 0; r < 4; ++r)
                oacc[i][j][r] = 0.f;

    for (int k = 0; k < 9; ++k) {
        f32x4 acc[4][4];
#pragma unroll
        for (int i = 0; i < 4; ++i)
#pragma unroll
            for (int j = 0; j < 4; ++j)
                acc[i][j] = {0.f, 0.f, 0.f, 0.f};

        gemm_tile(A, Bg + ((size_t)k * D_DIM + d0) * KD, m0, As, Bs, acc);

        const int s = c_offs[k];
#pragma unroll
        for (int i = 0; i < 4; ++i)
#pragma unroll
            for (int j = 0; j < 4; ++j)
#pragma unroll
                for (int r = 0; r < 4; ++r) {
                    int row = m0 + wr * 64 + i * 16 + lg * 4 + r;
                    int col = d0 + wc * 64 + j * 16 + lr;
                    int srow = (row & ~(L_DIM - 1)) | ((row + s + L_DIM) & (L_DIM - 1));
                    float g = 1.f / (1.f + __expf(-acc[i][j][r]));
                    oacc[i][j][r] += g * v_ws[(size_t)srow * D_DIM + col];
                }
    }

#pragma unroll
    for (int i = 0; i < 4; ++i)
#pragma unroll
        for (int j = 0; j < 4; ++j)
#pragma unroll
            for (int r = 0; r < 4; ++r) {
                int row = m0 + wr * 64 + i * 16 + lg * 4 + r;
                int col = d0 + wc * 64 + j * 16 + lr;
                out[(size_t)row * D_DIM + col] = oacc[i][j][r];
            }
}

// ---------- in-place LayerNorm over last dim ----------
__global__ __launch_bounds__(256) void ln_kernel(float* __restrict__ out,
                                                 const float* __restrict__ gamma,
                                                 const float* __restrict__ beta)
{
    const int row = blockIdx.x;
    const int tid = threadIdx.x;
    float4 v = *(float4*)&out[(size_t)row * D_DIM + tid * 4];
    float s  = v.x + v.y + v.z + v.w;
    float s2 = v.x * v.x + v.y * v.y + v.z * v.z + v.w * v.w;
#pragma unroll
    for (int off = 32; off > 0; off >>= 1) {
        s  += __shfl_down(s, off, 64);
        s2 += __shfl_down(s2, off, 64);
    }
    __shared__ float sh[8];
    const int wid = tid >> 6, lane = tid & 63;
    if (lane == 0) { sh[wid] = s; sh[4 + wid] = s2; }
    __syncthreads();
    if (tid == 0) {
        float ts = sh[0] + sh[1] + sh[2] + sh[3];
        float t2 = sh[4] + sh[5] + sh[6] + sh[7];
        sh[0] = ts; sh[1] = t2;
    }
    __syncthreads();
    const float mean = sh[0] * (1.f / (float)D_DIM);
    const float var  = sh[1] * (1.f / (float)D_DIM) - mean * mean;
    const float inv  = rsqrtf(var + 1e-5f);
    float4 g = *(const float4*)&gamma[tid * 4];
    float4 b = *(const float4*)&beta[tid * 4];
    v.x = (v.x - mean) * inv * g.x + b.x;
    v.y = (v.y - mean) * inv * g.y + b.y;
    v.z = (v.z - mean) * inv * g.z + b.z;
    v.w = (v.w - mean) * inv * g.w + b.w;
    *(float4*)&out[(size_t)row * D_DIM + tid * 4] = v;
}

extern "C" void kernel_launch(void* const* d_in, const int* in_sizes, int n_in,
                              void* d_out, int out_size, void* d_ws, size_t ws_size,
                              hipStream_t stream) {
    const float* x       = (const float*)d_in[0];   // (4,4096,1024)
    const float* gate_W  = (const float*)d_in[1];   // (9216,1024)
    const float* value_W = (const float*)d_in[2];   // (1024,1024)
    const float* gamma   = (const float*)d_in[3];   // (1024,)
    const float* beta    = (const float*)d_in[4];   // (1024,)
    float* out = (float*)d_out;                     // (4,4096,1024) f32

    char* ws = (char*)d_ws;
    unsigned short* a_bf = (unsigned short*)ws;                      // 32 MB
    unsigned short* bw_v = (unsigned short*)(ws + 33554432);         //  2 MB
    unsigned short* bw_g = (unsigned short*)(ws + 35651584);         // 18 MB
    float*          v_ws = (float*)(ws + 54525952);                  // 64 MB

    // 1. convert inputs to bf16 (plain round-to-nearest; K=1024)
    cvt_kernel<<<16384, 256, 0, stream>>>(x,       a_bf, (long)M_TOT * 1024);
    cvt_kernel<<<1024,  256, 0, stream>>>(value_W, bw_v, (long)1024  * 1024);
    cvt_kernel<<<9216,  256, 0, stream>>>(gate_W,  bw_g, (long)9216  * 1024);

    // 2. v = x @ value_W^T   (M=16384, N=1024, K=1024)
    v_gemm<<<dim3(8, 128), 256, 0, stream>>>(a_bf, bw_v, v_ws);

    // 3. gates GEMM + sigmoid + shifted-v gather + sum_k  -> pre-LN out
    gates_gemm<<<dim3(8, 128), 256, 0, stream>>>(a_bf, bw_g, v_ws, out);

    // 4. LayerNorm in place
    ln_kernel<<<16384, 256, 0, stream>>>(out, gamma, beta);
}